// Round 5
// baseline (194.705 us; speedup 1.0000x reference)
//
#include <hip/hip_runtime.h>

#define DEV __device__ __forceinline__

typedef __attribute__((ext_vector_type(4))) float f32x4;
typedef __attribute__((ext_vector_type(8))) __bf16 bf16x8;

typedef __attribute__((address_space(1))) const uint32_t gu32;
typedef __attribute__((address_space(3))) uint32_t su32;

// async global->LDS, 16B per lane. LDS dest = wave-uniform base + lane*16.
DEV void gload16(const void* g, void* s) {
  __builtin_amdgcn_global_load_lds((gu32*)(uintptr_t)g,
                                   (su32*)(uint32_t)(uintptr_t)s, 16, 0, 0);
}

DEV ushort bfbits(float f) { return __builtin_bit_cast(ushort, (__bf16)f); }

DEV bf16x8 lds8(const ushort* p) {
  return __builtin_bit_cast(bf16x8, *(const uint4*)(p));
}

template <int N> DEV void waitvm() {
  if constexpr (N == 0)      asm volatile("s_waitcnt vmcnt(0)" ::: "memory");
  else if constexpr (N == 3) asm volatile("s_waitcnt vmcnt(3)" ::: "memory");
  else if constexpr (N == 4) asm volatile("s_waitcnt vmcnt(4)" ::: "memory");
  else if constexpr (N == 6) asm volatile("s_waitcnt vmcnt(6)" ::: "memory");
  else                       asm volatile("s_waitcnt vmcnt(8)" ::: "memory");
}

DEV void barrier_hard() {
  __builtin_amdgcn_s_barrier();
  __builtin_amdgcn_sched_barrier(0);
}

// ---------------- fused fp32 -> bf16 convert (x + 4 weights; wq pre-scaled) ----------------
__global__ void cvt_all(const float* __restrict__ x, const float* __restrict__ wq,
                        const float* __restrict__ wk, const float* __restrict__ wv,
                        const float* __restrict__ wo, ushort* __restrict__ xb,
                        ushort* __restrict__ wb) {
  int i = blockIdx.x * blockDim.x + threadIdx.x;  // float4 id; total 2,097,152
  const float* src; ushort* dst; float scl = 1.0f; int j;
  if (i < 1048576) { src = x; dst = xb; j = i; }
  else {
    int t = (i - 1048576) >> 18;
    j = (i - 1048576) & 262143;
    src = t == 0 ? wq : (t == 1 ? wk : (t == 2 ? wv : wo));
    dst = wb + t * 1048576;
    if (t == 0) scl = 0.18033688011f;  // 0.125 * log2(e)
  }
  float4 v = ((const float4*)src)[j];
  ushort4 o;
  o.x = bfbits(v.x * scl); o.y = bfbits(v.y * scl);
  o.z = bfbits(v.z * scl); o.w = bfbits(v.w * scl);
  ((ushort4*)dst)[j] = o;
}

// ---------------- 3-buf counted-vmcnt GEMM: C[M,N] = A[M,1024] @ W[N,1024]^T ----------------
// Block tile 128 x (NFR*32). 4 waves (2x2); BK=32; LPS = gloads/wave/stage = 2 + NFR/2.
template <int NFR, int F32OUT>
DEV void gemm_core(const ushort* __restrict__ A, const ushort* __restrict__ W,
                   void* __restrict__ Cout, ushort* sA, ushort* sB) {
  const int tid = threadIdx.x;
  const int l = tid & 63, wv = tid >> 6;
  const int g = l >> 4, lan = l & 15;
  const int wr = wv >> 1, wc = wv & 1;
  const int brow = blockIdx.y * 128, bcol = blockIdx.x * (NFR * 32);
  const int ASZ = 128 * 32, BSZ = NFR * 32 * 32;
  const int NT = 32;
  constexpr int LPS = 2 + NFR / 2;

  f32x4 acc[4][NFR] = {};

  auto stage = [&](int buf, int t) {
    const int k0 = t * 32;
    ushort* dA = sA + buf * ASZ;
    ushort* dB = sB + buf * BSZ;
#pragma unroll
    for (int i = 0; i < 2; ++i) {
      int n = i * 256 + wv * 64 + l;
      int row = n >> 2, ss = n & 3, gs = (ss - (row >> 1)) & 3;
      gload16(A + (size_t)(brow + row) * 1024 + k0 + gs * 8,
              dA + (i * 256 + wv * 64) * 8);
    }
#pragma unroll
    for (int i = 0; i < NFR / 2; ++i) {
      int n = i * 256 + wv * 64 + l;
      int row = n >> 2, ss = n & 3, gs = (ss - (row >> 1)) & 3;
      gload16(W + (size_t)(bcol + row) * 1024 + k0 + gs * 8,
              dB + (i * 256 + wv * 64) * 8);
    }
  };

  auto compute = [&](int buf) {
    const ushort* cA = sA + buf * ASZ;
    const ushort* cB = sB + buf * BSZ;
    bf16x8 a[4], b[NFR];
#pragma unroll
    for (int fr = 0; fr < 4; ++fr) {
      int row = wr * 64 + fr * 16 + lan;
      a[fr] = lds8(cA + row * 32 + 8 * (((row >> 1) + g) & 3));
    }
#pragma unroll
    for (int fn = 0; fn < NFR; ++fn) {
      int row = wc * (NFR * 16) + fn * 16 + lan;
      b[fn] = lds8(cB + row * 32 + 8 * (((row >> 1) + g) & 3));
    }
    __builtin_amdgcn_s_setprio(1);
#pragma unroll
    for (int fr = 0; fr < 4; ++fr)
#pragma unroll
      for (int fn = 0; fn < NFR; ++fn)
        acc[fr][fn] = __builtin_amdgcn_mfma_f32_16x16x32_bf16(a[fr], b[fn], acc[fr][fn], 0, 0, 0);
    __builtin_amdgcn_s_setprio(0);
  };

  stage(0, 0);
#pragma unroll 1
  for (int t = 0; t < NT; ++t) {
    if (t + 1 < NT) {
      stage((t + 1) % 3, t + 1);
      waitvm<LPS>();            // drain stage(t), leave stage(t+1) in flight
    } else {
      waitvm<0>();
    }
    barrier_hard();
    compute(t % 3);
  }

#pragma unroll
  for (int fr = 0; fr < 4; ++fr)
#pragma unroll
    for (int fn = 0; fn < NFR; ++fn)
#pragma unroll
      for (int r = 0; r < 4; ++r) {
        int row = brow + wr * 64 + fr * 16 + g * 4 + r;
        int col = bcol + wc * (NFR * 16) + fn * 16 + lan;
        if (F32OUT)
          ((float*)Cout)[(size_t)row * 1024 + col] = acc[fr][fn][r];
        else
          ((ushort*)Cout)[(size_t)row * 1024 + col] = bfbits(acc[fr][fn][r]);
      }
}

__global__ __launch_bounds__(256) void gemm_qkv(
    const ushort* __restrict__ X, const ushort* __restrict__ Wb,
    ushort* __restrict__ Q, ushort* __restrict__ K, ushort* __restrict__ V) {
  __shared__ __align__(16) ushort sA[3 * 128 * 32];
  __shared__ __align__(16) ushort sB[3 * 128 * 32];
  const ushort* W = Wb + (size_t)blockIdx.z * 1048576;
  ushort* C = blockIdx.z == 0 ? Q : (blockIdx.z == 1 ? K : V);
  gemm_core<4, 0>(X, W, (void*)C, sA, sB);
}

__global__ __launch_bounds__(256) void gemm_out(
    const ushort* __restrict__ AO, const ushort* __restrict__ Wo, float* __restrict__ C) {
  __shared__ __align__(16) ushort sA[3 * 128 * 32];
  __shared__ __align__(16) ushort sB[3 * 64 * 32];
  gemm_core<2, 1>(AO, Wo, (void*)C, sA, sB);
}

// ---------------- V transpose: V[b,s,h*64+d] -> Vt[bh, d, s] ----------------
__global__ __launch_bounds__(256) void vt_kernel(const ushort* __restrict__ V,
                                                 ushort* __restrict__ Vt) {
  __shared__ __align__(16) ushort T[64 * 64];
  const int tid = threadIdx.x;
  const int stile = blockIdx.x, bh = blockIdx.y;
  const int b = bh >> 4, h = bh & 15;

#pragma unroll
  for (int i = 0; i < 2; ++i) {
    int m = i * 256 + tid;
    int s = m >> 3, dc = m & 7;
    uint4 v = *(const uint4*)(V + (size_t)(b * 2048 + stile * 64 + s) * 1024 + h * 64 + dc * 8);
    *(uint4*)(T + s * 64 + ((8 * dc) ^ (((s >> 3) & 7) << 3))) = v;
  }
  __syncthreads();

#pragma unroll
  for (int i = 0; i < 2; ++i) {
    int m = i * 256 + tid;
    int d = m >> 3, sb = m & 7;
    ushort tmp[8];
#pragma unroll
    for (int e = 0; e < 8; ++e)
      tmp[e] = T[(sb * 8 + e) * 64 + (d ^ (sb << 3))];
    uint4 o;
    o.x = (uint)tmp[0] | ((uint)tmp[1] << 16);
    o.y = (uint)tmp[2] | ((uint)tmp[3] << 16);
    o.z = (uint)tmp[4] | ((uint)tmp[5] << 16);
    o.w = (uint)tmp[6] | ((uint)tmp[7] << 16);
    *(uint4*)(Vt + ((size_t)bh * 64 + d) * 2048 + stile * 64 + sb * 8) = o;
  }
}

// ---------------- causal flash attention (exp2 domain; Q pre-scaled via Wq) ----------------
// 512 uniform blocks: block = (bh, pair pr) does q-tiles pr and 31-pr (33 KV-units).
// 4 waves x 16 q-rows; KV tile 64, triple-buffered, counted vmcnt.
__global__ __launch_bounds__(256) void attn_fwd(
    const ushort* __restrict__ Qm, const ushort* __restrict__ Km,
    const ushort* __restrict__ Vt, ushort* __restrict__ AO) {
  __shared__ __align__(16) ushort sK[3][64 * 64];
  __shared__ __align__(16) ushort sV[3][64 * 64];
  __shared__ __align__(16) ushort sP[4 * 16 * 64];

  const int tid = threadIdx.x;
  const int l = tid & 63, wv = tid >> 6;
  const int g = l >> 4, lan = l & 15;
  const int bid = blockIdx.x;
  const int idx = bid >> 3;
  const int bh = (bid & 7) * 4 + (idx >> 4);   // XCD-grouped: 4 bh per XCD
  const int pr = idx & 15;
  const int b = bh >> 4, h = bh & 15;

  ushort* Pw = sP + wv * 1024;

  auto stagekv = [&](int buf, int kt) {
#pragma unroll
    for (int i = 0; i < 2; ++i) {
      int n = i * 256 + wv * 64 + l;
      int row = n >> 3, ss = n & 7, gs = ss ^ (row & 7);
      gload16(Km + (size_t)(b * 2048 + kt * 64 + row) * 1024 + h * 64 + gs * 8,
              sK[buf] + (i * 256 + wv * 64) * 8);
      gload16(Vt + ((size_t)bh * 64 + row) * 2048 + kt * 64 + gs * 8,
              sV[buf] + (i * 256 + wv * 64) * 8);
    }
  };

#pragma unroll 1
  for (int seg = 0; seg < 2; ++seg) {
    const int qt = seg == 0 ? pr : 31 - pr;
    const int nkt = qt + 1;
    const int q0 = qt * 64 + wv * 16;
    const int qg = q0 + lan;

    if (seg) __syncthreads();   // full drain between segments (buffer reuse safety)

    bf16x8 qf[2];
#pragma unroll
    for (int kf = 0; kf < 2; ++kf)
      qf[kf] = __builtin_bit_cast(bf16x8,
          *(const uint4*)(Qm + (size_t)(b * 2048 + qg) * 1024 + h * 64 + kf * 32 + g * 8));

    float mrun = -1e30f, lrun = 0.f;
    f32x4 o[4];
#pragma unroll
    for (int of = 0; of < 4; ++of) o[of] = (f32x4){0.f, 0.f, 0.f, 0.f};

    stagekv(0, 0);

#pragma unroll 1
    for (int kt = 0; kt < nkt; ++kt) {
      const int buf = kt % 3;
      if (kt + 1 < nkt) {
        stagekv((kt + 1) % 3, kt + 1);
        waitvm<4>();            // drain stage(kt), leave stage(kt+1) flying
      } else {
        waitvm<0>();
      }
      barrier_hard();

      // S^T = K Q^T (exp2 domain)
      f32x4 sc[4];
      __builtin_amdgcn_s_setprio(1);
#pragma unroll
      for (int kvf = 0; kvf < 4; ++kvf) {
        f32x4 a2 = (f32x4){0.f, 0.f, 0.f, 0.f};
#pragma unroll
        for (int kf = 0; kf < 2; ++kf) {
          int row = kvf * 16 + lan;
          bf16x8 kb = lds8(sK[buf] + row * 64 + 8 * ((kf * 4 + g) ^ (row & 7)));
          a2 = __builtin_amdgcn_mfma_f32_16x16x32_bf16(kb, qf[kf], a2, 0, 0, 0);
        }
        sc[kvf] = a2;
      }
      __builtin_amdgcn_s_setprio(0);

      if (kt == qt) {           // mask only the diagonal tile
#pragma unroll
        for (int kvf = 0; kvf < 4; ++kvf)
#pragma unroll
          for (int r = 0; r < 4; ++r) {
            int kvg = kt * 64 + kvf * 16 + 4 * g + r;
            sc[kvf][r] = (kvg <= qg) ? sc[kvf][r] : -1e30f;
          }
      }

      float mx = sc[0][0];
#pragma unroll
      for (int kvf = 0; kvf < 4; ++kvf)
#pragma unroll
        for (int r = 0; r < 4; ++r) mx = fmaxf(mx, sc[kvf][r]);
      mx = fmaxf(mx, __shfl_xor(mx, 16));
      mx = fmaxf(mx, __shfl_xor(mx, 32));

      const bool noresc = __all(mx <= mrun + 8.0f);   // defer-max (log2 domain)
      const float mnew = noresc ? mrun : fmaxf(mrun, mx);

      float rs = 0.f;
#pragma unroll
      for (int kvf = 0; kvf < 4; ++kvf)
#pragma unroll
        for (int r = 0; r < 4; ++r) {
          float p = __builtin_exp2f(sc[kvf][r] - mnew);
          sc[kvf][r] = p;
          rs += p;
        }
      rs += __shfl_xor(rs, 16);
      rs += __shfl_xor(rs, 32);

      if (noresc) {
        lrun += rs;
      } else {
        float alpha = __builtin_exp2f(mrun - mnew);
        mrun = mnew;
        lrun = lrun * alpha + rs;
        float al[4];
#pragma unroll
        for (int r = 0; r < 4; ++r) al[r] = __shfl(alpha, g * 4 + r);
#pragma unroll
        for (int of = 0; of < 4; ++of)
#pragma unroll
          for (int r = 0; r < 4; ++r) o[of][r] *= al[r];
      }

      // write P tile (packed, swizzled)
#pragma unroll
      for (int kvf = 0; kvf < 4; ++kvf) {
        ushort4 pk;
        pk.x = bfbits(sc[kvf][0]); pk.y = bfbits(sc[kvf][1]);
        pk.z = bfbits(sc[kvf][2]); pk.w = bfbits(sc[kvf][3]);
        *(ushort4*)(Pw + lan * 64 + ((16 * kvf + 4 * g) ^ ((lan & 7) << 3))) = pk;
      }
      bf16x8 pa[2];
#pragma unroll
      for (int kf = 0; kf < 2; ++kf)
        pa[kf] = lds8(Pw + lan * 64 + ((32 * kf + 8 * g) ^ ((lan & 7) << 3)));

      __builtin_amdgcn_s_setprio(1);
#pragma unroll
      for (int of = 0; of < 4; ++of)
#pragma unroll
        for (int kf = 0; kf < 2; ++kf) {
          int row = of * 16 + lan;
          bf16x8 vb = lds8(sV[buf] + row * 64 + 8 * ((kf * 4 + g) ^ (row & 7)));
          o[of] = __builtin_amdgcn_mfma_f32_16x16x32_bf16(pa[kf], vb, o[of], 0, 0, 0);
        }
      __builtin_amdgcn_s_setprio(0);
    }

#pragma unroll
    for (int r = 0; r < 4; ++r) {
      float il = 1.0f / __shfl(lrun, g * 4 + r);
#pragma unroll
      for (int of = 0; of < 4; ++of) {
        int grow = qt * 64 + wv * 16 + g * 4 + r;
        AO[(size_t)(b * 2048 + grow) * 1024 + h * 64 + of * 16 + lan] = bfbits(o[of][r] * il);
      }
    }
  }
}

// ---------------- launch ----------------
extern "C" void kernel_launch(void* const* d_in, const int* in_sizes, int n_in,
                              void* d_out, int out_size, void* d_ws, size_t ws_size,
                              hipStream_t stream) {
  const float* x  = (const float*)d_in[0];
  const float* wq = (const float*)d_in[1];
  const float* wk = (const float*)d_in[2];
  const float* wv = (const float*)d_in[3];
  const float* wo = (const float*)d_in[4];
  float* out = (float*)d_out;

  char* ws = (char*)d_ws;
  const size_t MB = 1ull << 20;
  ushort* xb = (ushort*)(ws + 0);         // 8 MB; reused as Vt after gemm_qkv
  ushort* wb = (ushort*)(ws + 8 * MB);    // 8 MB: wq|wk|wv|wo bf16
  ushort* Q  = (ushort*)(ws + 16 * MB);
  ushort* K  = (ushort*)(ws + 24 * MB);
  ushort* V  = (ushort*)(ws + 32 * MB);
  ushort* AO = (ushort*)(ws + 40 * MB);
  ushort* Vt = (ushort*)(ws + 0);
  ushort* wob = wb + 3 * 1048576;

  cvt_all<<<8192, 256, 0, stream>>>(x, wq, wk, wv, wo, xb, wb);
  gemm_qkv<<<dim3(8, 32, 3), 256, 0, stream>>>(xb, wb, Q, K, V);
  vt_kernel<<<dim3(32, 32), 256, 0, stream>>>(V, Vt);
  attn_fwd<<<512, 256, 0, stream>>>(Q, K, Vt, AO);
  gemm_out<<<dim3(16, 32), 256, 0, stream>>>(AO, wob, out);
}